// Round 4
// baseline (191.178 us; speedup 1.0000x reference)
//
#include <hip/hip_runtime.h>

typedef float f4 __attribute__((ext_vector_type(4)));
typedef int   i4 __attribute__((ext_vector_type(4)));

#define TDIM 128     // TOKEN_DIM
#define VNUM 8       // VIRTUAL_NUM
#define NSIM 25      // blocks 0..24: sim (25*256 = 6400 = T*T)
#define NSPECIAL 26  // + block 25: t-writer/query
#define VPT 8        // float4s per thread in bulk (128 B/thread)
#define BLK_ELEMS (256 * VPT)   // float4s per bulk block

__global__ __launch_bounds__(256) void fused_kernel(
    const f4* __restrict__ x4,
    const i4* __restrict__ e4,
    const i4* __restrict__ a4,
    const float* __restrict__ token_list,
    const float* __restrict__ vir_list,
    const int*   __restrict__ attr_index,
    const int*   __restrict__ query,
    f4* __restrict__ ox4,          // x part of x_cat (rows T..T+N-1)
    f4* __restrict__ oe4,          // shifted_edge_index as float
    f4* __restrict__ oa4,          // attr_mask as float
    float* __restrict__ out_sim,   // token_sim [T*T]
    float* __restrict__ out_adj,   // inner_adj [T*T]
    float* __restrict__ out_t,     // t rows of x_cat [T*TDIM]
    float* __restrict__ out_query, // query as float [NQ]
    long nx4, long ne4, long na4,
    long xb, long eb,              // block counts for x / edge segments
    int A, int T, int NQ)
{
    const int bid = blockIdx.x;
    const int tid = threadIdx.x;

    if (bid >= NSPECIAL) {
        long b = bid - NSPECIAL;
        if (b < xb) {
            // ----- x copy: 8 x float4 per thread, loads batched -----
            long base = b * BLK_ELEMS + tid;
            f4 v[VPT];
#pragma unroll
            for (int u = 0; u < VPT; ++u) {
                long i = base + (long)u * 256;
                if (i < nx4) v[u] = __builtin_nontemporal_load(&x4[i]);
            }
#pragma unroll
            for (int u = 0; u < VPT; ++u) {
                long i = base + (long)u * 256;
                if (i < nx4) __builtin_nontemporal_store(v[u], &ox4[i]);
            }
        } else if (b < xb + eb) {
            // ----- edge_index + T, int -> float -----
            long base = (b - xb) * BLK_ELEMS + tid;
            i4 v[VPT];
#pragma unroll
            for (int u = 0; u < VPT; ++u) {
                long i = base + (long)u * 256;
                if (i < ne4) v[u] = __builtin_nontemporal_load(&e4[i]);
            }
#pragma unroll
            for (int u = 0; u < VPT; ++u) {
                long i = base + (long)u * 256;
                if (i < ne4) {
                    f4 f;
                    f.x = (float)(v[u].x + T);
                    f.y = (float)(v[u].y + T);
                    f.z = (float)(v[u].z + T);
                    f.w = (float)(v[u].w + T);
                    __builtin_nontemporal_store(f, &oe4[i]);
                }
            }
        } else {
            // ----- x_attr != 0 -> 0/1 float -----
            long base = (b - xb - eb) * BLK_ELEMS + tid;
            i4 v[VPT];
#pragma unroll
            for (int u = 0; u < VPT; ++u) {
                long i = base + (long)u * 256;
                if (i < na4) v[u] = __builtin_nontemporal_load(&a4[i]);
            }
#pragma unroll
            for (int u = 0; u < VPT; ++u) {
                long i = base + (long)u * 256;
                if (i < na4) {
                    f4 f;
                    f.x = (v[u].x != 0) ? 1.0f : 0.0f;
                    f.y = (v[u].y != 0) ? 1.0f : 0.0f;
                    f.z = (v[u].z != 0) ? 1.0f : 0.0f;
                    f.w = (v[u].w != 0) ? 1.0f : 0.0f;
                    __builtin_nontemporal_store(f, &oa4[i]);
                }
            }
        }
        return;
    }

    if (bid < NSIM) {
        // ----- sim blocks: p = bid*256 + tid indexes the T*T sim matrix -----
        int p = bid * 256 + tid;
        if (p >= T * T) return;
        int i = p / T;
        int j = p - i * T;
        const float* pi;
        const float* pj;
        {
            int r = i;
            pi = (r < A) ? token_list + (long)attr_index[r] * TDIM
               : (r < A + VNUM) ? (const float*)0
               : vir_list + (long)(r - A - VNUM) * TDIM;
            r = j;
            pj = (r < A) ? token_list + (long)attr_index[r] * TDIM
               : (r < A + VNUM) ? (const float*)0
               : vir_list + (long)(r - A - VNUM) * TDIM;
        }
        float acc = 0.0f;
        if (pi && pj) {
            const f4* a = (const f4*)pi;
            const f4* b = (const f4*)pj;
#pragma unroll
            for (int k = 0; k < TDIM / 4; ++k) {
                f4 av = a[k];
                f4 bv = b[k];
                acc += av.x * bv.x + av.y * bv.y + av.z * bv.z + av.w * bv.w;
            }
        }
        float s = 1.0f / (1.0f + __expf(-acc));
        out_sim[p] = s;
        out_adj[p] = (s >= 0.01f) ? 1.0f : 0.0f;
        return;
    }

    // ----- t-writer block: t rows of x_cat + query passthrough -----
    for (int e = tid; e < T * TDIM; e += 256) {
        int r = e >> 7;            // / TDIM
        int c = e & (TDIM - 1);
        float v = (r < A) ? token_list[(long)attr_index[r] * TDIM + c]
                : (r < A + VNUM) ? 0.0f
                : vir_list[(long)(r - A - VNUM) * TDIM + c];
        out_t[e] = v;
    }
    if (tid < NQ) out_query[tid] = (float)query[tid];
}

extern "C" void kernel_launch(void* const* d_in, const int* in_sizes, int n_in,
                              void* d_out, int out_size, void* d_ws, size_t ws_size,
                              hipStream_t stream) {
    const float* x          = (const float*)d_in[0];
    const float* token_list = (const float*)d_in[1];
    const float* vir_list   = (const float*)d_in[2];
    const int*   attr_index = (const int*)d_in[3];
    const int*   x_attr     = (const int*)d_in[4];
    const int*   query      = (const int*)d_in[5];
    const int*   edge_index = (const int*)d_in[6];
    float* out = (float*)d_out;

    const int  d      = TDIM;
    const int  A      = in_sizes[3];          // 64
    const int  T      = A + 2 * VNUM;         // 80
    const long n_x    = (long)in_sizes[0];    // N*d
    const long N      = n_x / d;
    const long n_attr = (long)in_sizes[4];    // N*A
    const int  NQ     = in_sizes[5];
    const long n_edge = (long)in_sizes[6];    // 2*E

    // Flat float32 output offsets, reference return order.
    const long O_xcat  = 0;
    const long O_sim   = O_xcat + (T + N) * (long)d;
    const long O_adj   = O_sim + (long)T * T;
    const long O_edge  = O_adj + (long)T * T;
    const long O_attr  = O_edge + n_edge;
    const long O_query = O_attr + n_attr;

    const long nx4 = n_x / 4, ne4 = n_edge / 4, na4 = n_attr / 4;
    const long xb = (nx4 + BLK_ELEMS - 1) / BLK_ELEMS;
    const long eb = (ne4 + BLK_ELEMS - 1) / BLK_ELEMS;
    const long ab = (na4 + BLK_ELEMS - 1) / BLK_ELEMS;
    const long grid = NSPECIAL + xb + eb + ab;

    fused_kernel<<<(int)grid, 256, 0, stream>>>(
        (const f4*)x, (const i4*)edge_index, (const i4*)x_attr,
        token_list, vir_list, attr_index, query,
        (f4*)(out + O_xcat + (long)T * d),
        (f4*)(out + O_edge),
        (f4*)(out + O_attr),
        out + O_sim, out + O_adj, out + O_xcat, out + O_query,
        nx4, ne4, na4, xb, eb, A, T, NQ);
}

// Round 5
// 152.622 us; speedup vs baseline: 1.2526x; 1.2526x over previous
//
#include <hip/hip_runtime.h>

typedef float f4 __attribute__((ext_vector_type(4)));
typedef int   i4 __attribute__((ext_vector_type(4)));

#define TDIM 128     // TOKEN_DIM
#define VNUM 8       // VIRTUAL_NUM
#define NSIM 25      // blocks 0..24: sim (25*256 = 6400 = T*T)
#define NSPECIAL 26  // + block 25: t-writer/query
#define VPT 4        // float4s per thread in bulk (64 B/thread) — VPT sweep: 1->5.51, 4->5.92, 8->4.69 TB/s
#define BLK_ELEMS (256 * VPT)   // float4s per bulk block

__global__ __launch_bounds__(256) void fused_kernel(
    const f4* __restrict__ x4,
    const i4* __restrict__ e4,
    const i4* __restrict__ a4,
    const float* __restrict__ token_list,
    const float* __restrict__ vir_list,
    const int*   __restrict__ attr_index,
    const int*   __restrict__ query,
    f4* __restrict__ ox4,          // x part of x_cat (rows T..T+N-1)
    f4* __restrict__ oe4,          // shifted_edge_index as float
    f4* __restrict__ oa4,          // attr_mask as float
    float* __restrict__ out_sim,   // token_sim [T*T]
    float* __restrict__ out_adj,   // inner_adj [T*T]
    float* __restrict__ out_t,     // t rows of x_cat [T*TDIM]
    float* __restrict__ out_query, // query as float [NQ]
    long nx4, long ne4, long na4,
    long xb, long eb,              // block counts for x / edge segments
    int A, int T, int NQ)
{
    const int bid = blockIdx.x;
    const int tid = threadIdx.x;

    if (bid >= NSPECIAL) {
        long b = bid - NSPECIAL;
        if (b < xb) {
            // ----- x copy: 4 x float4 per thread, loads batched -----
            long base = b * BLK_ELEMS + tid;
            f4 v[VPT];
#pragma unroll
            for (int u = 0; u < VPT; ++u) {
                long i = base + (long)u * 256;
                if (i < nx4) v[u] = __builtin_nontemporal_load(&x4[i]);
            }
#pragma unroll
            for (int u = 0; u < VPT; ++u) {
                long i = base + (long)u * 256;
                if (i < nx4) __builtin_nontemporal_store(v[u], &ox4[i]);
            }
        } else if (b < xb + eb) {
            // ----- edge_index + T, int -> float -----
            long base = (b - xb) * BLK_ELEMS + tid;
            i4 v[VPT];
#pragma unroll
            for (int u = 0; u < VPT; ++u) {
                long i = base + (long)u * 256;
                if (i < ne4) v[u] = __builtin_nontemporal_load(&e4[i]);
            }
#pragma unroll
            for (int u = 0; u < VPT; ++u) {
                long i = base + (long)u * 256;
                if (i < ne4) {
                    f4 f;
                    f.x = (float)(v[u].x + T);
                    f.y = (float)(v[u].y + T);
                    f.z = (float)(v[u].z + T);
                    f.w = (float)(v[u].w + T);
                    __builtin_nontemporal_store(f, &oe4[i]);
                }
            }
        } else {
            // ----- x_attr != 0 -> 0/1 float -----
            long base = (b - xb - eb) * BLK_ELEMS + tid;
            i4 v[VPT];
#pragma unroll
            for (int u = 0; u < VPT; ++u) {
                long i = base + (long)u * 256;
                if (i < na4) v[u] = __builtin_nontemporal_load(&a4[i]);
            }
#pragma unroll
            for (int u = 0; u < VPT; ++u) {
                long i = base + (long)u * 256;
                if (i < na4) {
                    f4 f;
                    f.x = (v[u].x != 0) ? 1.0f : 0.0f;
                    f.y = (v[u].y != 0) ? 1.0f : 0.0f;
                    f.z = (v[u].z != 0) ? 1.0f : 0.0f;
                    f.w = (v[u].w != 0) ? 1.0f : 0.0f;
                    __builtin_nontemporal_store(f, &oa4[i]);
                }
            }
        }
        return;
    }

    if (bid < NSIM) {
        // ----- sim blocks: p = bid*256 + tid indexes the T*T sim matrix -----
        int p = bid * 256 + tid;
        if (p >= T * T) return;
        int i = p / T;
        int j = p - i * T;
        const float* pi;
        const float* pj;
        {
            int r = i;
            pi = (r < A) ? token_list + (long)attr_index[r] * TDIM
               : (r < A + VNUM) ? (const float*)0
               : vir_list + (long)(r - A - VNUM) * TDIM;
            r = j;
            pj = (r < A) ? token_list + (long)attr_index[r] * TDIM
               : (r < A + VNUM) ? (const float*)0
               : vir_list + (long)(r - A - VNUM) * TDIM;
        }
        float acc = 0.0f;
        if (pi && pj) {
            const f4* a = (const f4*)pi;
            const f4* b = (const f4*)pj;
#pragma unroll
            for (int k = 0; k < TDIM / 4; ++k) {
                f4 av = a[k];
                f4 bv = b[k];
                acc += av.x * bv.x + av.y * bv.y + av.z * bv.z + av.w * bv.w;
            }
        }
        float s = 1.0f / (1.0f + __expf(-acc));
        out_sim[p] = s;
        out_adj[p] = (s >= 0.01f) ? 1.0f : 0.0f;
        return;
    }

    // ----- t-writer block: t rows of x_cat + query passthrough -----
    for (int e = tid; e < T * TDIM; e += 256) {
        int r = e >> 7;            // / TDIM
        int c = e & (TDIM - 1);
        float v = (r < A) ? token_list[(long)attr_index[r] * TDIM + c]
                : (r < A + VNUM) ? 0.0f
                : vir_list[(long)(r - A - VNUM) * TDIM + c];
        out_t[e] = v;
    }
    if (tid < NQ) out_query[tid] = (float)query[tid];
}

extern "C" void kernel_launch(void* const* d_in, const int* in_sizes, int n_in,
                              void* d_out, int out_size, void* d_ws, size_t ws_size,
                              hipStream_t stream) {
    const float* x          = (const float*)d_in[0];
    const float* token_list = (const float*)d_in[1];
    const float* vir_list   = (const float*)d_in[2];
    const int*   attr_index = (const int*)d_in[3];
    const int*   x_attr     = (const int*)d_in[4];
    const int*   query      = (const int*)d_in[5];
    const int*   edge_index = (const int*)d_in[6];
    float* out = (float*)d_out;

    const int  d      = TDIM;
    const int  A      = in_sizes[3];          // 64
    const int  T      = A + 2 * VNUM;         // 80
    const long n_x    = (long)in_sizes[0];    // N*d
    const long N      = n_x / d;
    const long n_attr = (long)in_sizes[4];    // N*A
    const int  NQ     = in_sizes[5];
    const long n_edge = (long)in_sizes[6];    // 2*E

    // Flat float32 output offsets, reference return order.
    const long O_xcat  = 0;
    const long O_sim   = O_xcat + (T + N) * (long)d;
    const long O_adj   = O_sim + (long)T * T;
    const long O_edge  = O_adj + (long)T * T;
    const long O_attr  = O_edge + n_edge;
    const long O_query = O_attr + n_attr;

    const long nx4 = n_x / 4, ne4 = n_edge / 4, na4 = n_attr / 4;
    const long xb = (nx4 + BLK_ELEMS - 1) / BLK_ELEMS;
    const long eb = (ne4 + BLK_ELEMS - 1) / BLK_ELEMS;
    const long ab = (na4 + BLK_ELEMS - 1) / BLK_ELEMS;
    const long grid = NSPECIAL + xb + eb + ab;

    fused_kernel<<<(int)grid, 256, 0, stream>>>(
        (const f4*)x, (const i4*)edge_index, (const i4*)x_attr,
        token_list, vir_list, attr_index, query,
        (f4*)(out + O_xcat + (long)T * d),
        (f4*)(out + O_edge),
        (f4*)(out + O_attr),
        out + O_sim, out + O_adj, out + O_xcat, out + O_query,
        nx4, ne4, na4, xb, eb, A, T, NQ);
}